// Round 1
// 2149.402 us; speedup vs baseline: 1.1298x; 1.1298x over previous
//
#include <hip/hip_runtime.h>
#include <cstdint>

#define BATCH   65536
#define IN_DIM  640
#define LAT_DIM 2560
#define KSEL    32

typedef short  v8s __attribute__((ext_vector_type(8)));
typedef float  v4f __attribute__((ext_vector_type(4)));

__device__ inline void async_load16(void* lds, const void* g) {
  __builtin_amdgcn_global_load_lds(
      (const __attribute__((address_space(1))) unsigned int*)g,
      (__attribute__((address_space(3))) unsigned int*)lds, 16, 0, 0);
}

__device__ inline unsigned short f2bf(float v) {
  unsigned int b = __float_as_uint(v);
  return (unsigned short)((b + 0x7fffu + ((b >> 16) & 1u)) >> 16);
}

// ============ conv fp32 -> bf16, 8 elems/thread ============
__global__ __launch_bounds__(256) void conv_bf16(
    const float* __restrict__ src, unsigned short* __restrict__ dst, int n8)
{
  int i = blockIdx.x * 256 + threadIdx.x;
  if (i >= n8) return;
  const float4* s4 = (const float4*)(src) + i * 2;
  float4 a = s4[0], b = s4[1];
  ushort4 lo = make_ushort4(f2bf(a.x), f2bf(a.y), f2bf(a.z), f2bf(a.w));
  ushort4 hi = make_ushort4(f2bf(b.x), f2bf(b.y), f2bf(b.z), f2bf(b.w));
  *(ushort4*)(dst + (size_t)i * 8)     = lo;
  *(ushort4*)(dst + (size_t)i * 8 + 4) = hi;
}

// ============ transpose Wd [640][2560] -> WdT bf16 [2560][640] ============
__global__ __launch_bounds__(256) void transpose_wd(
    const float* __restrict__ Wd, unsigned short* __restrict__ WdT)
{
  __shared__ float tile[32][33];
  const int tx = threadIdx.x & 31;
  const int ty = threadIdx.x >> 5;
  const int l0 = (blockIdx.x % (LAT_DIM / 32)) * 32;
  const int i0 = (blockIdx.x / (LAT_DIM / 32)) * 32;
#pragma unroll
  for (int s = 0; s < 4; ++s)
    tile[ty + 8 * s][tx] = Wd[(size_t)(i0 + ty + 8 * s) * LAT_DIM + l0 + tx];
  __syncthreads();
#pragma unroll
  for (int s = 0; s < 4; ++s)
    WdT[(size_t)(l0 + ty + 8 * s) * IN_DIM + i0 + tx] = f2bf(tile[tx][ty + 8 * s]);
}

// ============ encoder: lat = x @ We^T + be, bf16 MFMA, fp32 out ============
__global__ __launch_bounds__(256) void encoder_mfma(
    const unsigned short* __restrict__ xb,   // bf16 [B][640]
    const unsigned short* __restrict__ web,  // bf16 [2560][640]
    const float* __restrict__ be,
    float* __restrict__ lat)                 // fp32 [B][2560]
{
  __shared__ unsigned short As[128 * 32];
  __shared__ unsigned short Bs[128 * 32];

  const int t = threadIdx.x, lane = t & 63, wave = t >> 6;
  const int nt = blockIdx.x % (LAT_DIM / 128);
  const int mt = blockIdx.x / (LAT_DIM / 128);
  const int m0 = mt * 128, n0 = nt * 128;
  const int mBase = (wave & 1) * 64, nBase = (wave >> 1) * 64;

  v4f acc[4][4];
#pragma unroll
  for (int mi = 0; mi < 4; ++mi)
#pragma unroll
    for (int ni = 0; ni < 4; ++ni) acc[mi][ni] = (v4f){0.f, 0.f, 0.f, 0.f};

  const int s1 = t, s2 = t + 256;
  const int r1 = s1 >> 2, q1 = s1 & 3, r2 = s2 >> 2, q2 = s2 & 3;
  const unsigned short* gA1 = xb  + (size_t)(m0 + r1) * IN_DIM + q1 * 8;
  const unsigned short* gA2 = xb  + (size_t)(m0 + r2) * IN_DIM + q2 * 8;
  const unsigned short* gB1 = web + (size_t)(n0 + r1) * IN_DIM + q1 * 8;
  const unsigned short* gB2 = web + (size_t)(n0 + r2) * IN_DIM + q2 * 8;
  unsigned short* lA1 = As + s1 * 8;  unsigned short* lA2 = As + s2 * 8;
  unsigned short* lB1 = Bs + s1 * 8;  unsigned short* lB2 = Bs + s2 * 8;

  const int arow = (mBase + (lane & 15)) * 32 + (lane >> 4) * 8;
  const int brow = (nBase + (lane & 15)) * 32 + (lane >> 4) * 8;

  for (int kt = 0; kt < IN_DIM; kt += 32) {
    async_load16(lA1, gA1 + kt);
    async_load16(lA2, gA2 + kt);
    async_load16(lB1, gB1 + kt);
    async_load16(lB2, gB2 + kt);
    __syncthreads();
    v8s a[4], b[4];
#pragma unroll
    for (int mi = 0; mi < 4; ++mi) a[mi] = *(const v8s*)(As + arow + mi * 16 * 32);
#pragma unroll
    for (int ni = 0; ni < 4; ++ni) b[ni] = *(const v8s*)(Bs + brow + ni * 16 * 32);
#pragma unroll
    for (int mi = 0; mi < 4; ++mi)
#pragma unroll
      for (int ni = 0; ni < 4; ++ni)
        acc[mi][ni] = __builtin_amdgcn_mfma_f32_16x16x32_bf16(a[mi], b[ni], acc[mi][ni], 0, 0, 0);
    __syncthreads();
  }

  float bev[4];
#pragma unroll
  for (int ni = 0; ni < 4; ++ni) bev[ni] = be[n0 + nBase + ni * 16 + (lane & 15)];
#pragma unroll
  for (int mi = 0; mi < 4; ++mi) {
    const int grow0 = m0 + mBase + mi * 16 + (lane >> 4) * 4;
#pragma unroll
    for (int ni = 0; ni < 4; ++ni) {
      const int gcol = n0 + nBase + ni * 16 + (lane & 15);
#pragma unroll
      for (int r = 0; r < 4; ++r)
        lat[(size_t)(grow0 + r) * LAT_DIM + gcol] = acc[mi][ni][r] + bev[ni];
    }
  }
}

// ============ topk v2: threshold + ballot compaction (unchanged) ============
// rank passes replaced by EXACT bit-bisection on float bit patterns:
//   invariant: #{> hi} <= 31, #{> lo} >= 32; terminate at hi-lo==1ulp ->
//   hi is exactly the rank-31 value (attained, all tie cases correct).
// Selected set == old O(cnt) rank loops (gt-set + lowest-index equals);
// only the ws slot ORDER differs (decoder/scatter are order-invariant).
#define TK_CAP 160
#define TK_WIN 0.012f

__global__ __launch_bounds__(256) void topk2(
    float* __restrict__ lat,            // dense noisy in, sparse out (in place)
    const float* __restrict__ x,        // fp32 [B][640]
    const float* __restrict__ We,       // fp32 [2560][640]
    const float* __restrict__ be,
    float* __restrict__ ws_val, int* __restrict__ ws_idx)
{
  __shared__ float cval[4][TK_CAP];
  __shared__ int   cidx[4][TK_CAP];
  __shared__ int   winl[4][48];
  __shared__ int   seli[4][KSEL];

  const int wave = threadIdx.x >> 6, lane = threadIdx.x & 63;
  const size_t row = (size_t)blockIdx.x * 4 + wave;
  float* rowp = lat + row * LAT_DIM;
  const unsigned long long lmask = (1ull << lane) - 1ull;

  float v[40];
#pragma unroll
  for (int j = 0; j < 40; ++j) v[j] = rowp[lane + 64 * j];

  // row RMS -> initial threshold at ~rank-64 quantile
  float ss = 0.f;
#pragma unroll
  for (int j = 0; j < 40; ++j) ss = fmaf(v[j], v[j], ss);
#pragma unroll
  for (int off = 32; off > 0; off >>= 1) ss += __shfl_xor(ss, off, 64);
  const float sigma = sqrtf(ss * (1.0f / LAT_DIM));
  float T = 1.96f * sigma;

  int cnt = 0;
  for (int it = 0; it < 40; ++it) {
    cnt = 0;
#pragma unroll
    for (int j = 0; j < 40; ++j) cnt += (int)__popcll(__ballot(v[j] > T));
    if (cnt >= 44 && cnt <= TK_CAP) break;
    T += (cnt < 44) ? (-0.25f * sigma) : (0.10f * sigma);
  }

  // collect candidates (val, idx) via ballot compaction; slot order is
  // ascending latent index (j-major then lane) -> cidx strictly increasing.
  int base = 0;
#pragma unroll
  for (int j = 0; j < 40; ++j) {
    unsigned long long b = __ballot(v[j] > T);
    if (v[j] > T) {
      int p = base + (int)__popcll(b & lmask);
      if (p < TK_CAP) { cval[wave][p] = v[j]; cidx[wave][p] = lane + 64 * j; }
    }
    base += (int)__popcll(b);
  }
  cnt = base < TK_CAP ? base : TK_CAP;

  // ---- candidates into registers: 3 slots per lane ----
  const int e0 = lane, e1 = lane + 64, e2 = lane + 128;
  float c0 = (e0 < cnt) ? cval[wave][e0] : -3e38f;
  float c1 = (e1 < cnt) ? cval[wave][e1] : -3e38f;
  float c2 = (e2 < cnt) ? cval[wave][e2] : -3e38f;
  int   i0 = (e0 < cnt) ? cidx[wave][e0] : 0;
  int   i1 = (e1 < cnt) ? cidx[wave][e1] : 0;
  int   i2 = (e2 < cnt) ? cidx[wave][e2] : 0;

  // ---- bisect 1: v32 = exact rank-31 noisy value ----
  float mx = fmaxf(fmaxf(c0, c1), c2);
#pragma unroll
  for (int off = 32; off > 0; off >>= 1) mx = fmaxf(mx, __shfl_xor(mx, off, 64));
  unsigned lo_b = __float_as_uint(fmaxf(T, 0.f));   // all candidates > T (positive regime)
  unsigned hi_b = __float_as_uint(mx);
  while (hi_b - lo_b > 1u) {
    unsigned mid_b = lo_b + ((hi_b - lo_b) >> 1);
    float midf = __uint_as_float(mid_b);
    int n = (int)__popcll(__ballot(c0 > midf)) + (int)__popcll(__ballot(c1 > midf))
          + (int)__popcll(__ballot(c2 > midf));
    if (n >= KSEL) lo_b = mid_b; else hi_b = mid_b;
  }
  const float v32 = __uint_as_float(hi_b);

  // ---- eligibility + window flags from NOISY values (matches old order) ----
  const bool el0 = (e0 < cnt) && (c0 >= v32 - TK_WIN);
  const bool el1 = (e1 < cnt) && (c1 >= v32 - TK_WIN);
  const bool el2 = (e2 < cnt) && (c2 >= v32 - TK_WIN);
  const bool w0  = (e0 < cnt) && (fabsf(c0 - v32) <= TK_WIN);
  const bool w1  = (e1 < cnt) && (fabsf(c1 - v32) <= TK_WIN);
  const bool w2  = (e2 < cnt) && (fabsf(c2 - v32) <= TK_WIN);

  int wbase = 0;
  {
    unsigned long long b = __ballot(w0);
    if (w0) { int p = wbase + (int)__popcll(b & lmask); if (p < 48) winl[wave][p] = e0; }
    wbase += (int)__popcll(b);
    b = __ballot(w1);
    if (w1) { int p = wbase + (int)__popcll(b & lmask); if (p < 48) winl[wave][p] = e1; }
    wbase += (int)__popcll(b);
    b = __ballot(w2);
    if (w2) { int p = wbase + (int)__popcll(b & lmask); if (p < 48) winl[wave][p] = e2; }
    wbase += (int)__popcll(b);
  }
  const int wcnt = wbase < 48 ? wbase : 48;

  // exact recompute: strictly-sequential ascending-k fp32 fma chain (matches np/BLAS order)
  if (lane < wcnt) {
    int slot = winl[wave][lane];
    int c = cidx[wave][slot];
    const float4* x4 = (const float4*)(x + row * IN_DIM);
    const float4* w4 = (const float4*)(We + (size_t)c * IN_DIM);
    float acc = 0.f;
#pragma unroll 4
    for (int i = 0; i < IN_DIM / 4; ++i) {
      float4 xv = x4[i], wv = w4[i];
      acc = fmaf(xv.x, wv.x, acc);
      acc = fmaf(xv.y, wv.y, acc);
      acc = fmaf(xv.z, wv.z, acc);
      acc = fmaf(xv.w, wv.w, acc);
    }
    cval[wave][slot] = acc + be[c];
  }

  // refresh registers with substituted values (window slots changed, cross-lane)
  if (e0 < cnt) c0 = cval[wave][e0];
  if (e1 < cnt) c1 = cval[wave][e1];
  if (e2 < cnt) c2 = cval[wave][e2];

  // ---- bisect 2: exact rank-31 among ELIGIBLE with substituted values ----
  const float q0 = el0 ? c0 : -3e38f;
  const float q1 = el1 ? c1 : -3e38f;
  const float q2 = el2 ? c2 : -3e38f;
  float mx2 = fmaxf(fmaxf(q0, q1), q2);
#pragma unroll
  for (int off = 32; off > 0; off >>= 1) mx2 = fmaxf(mx2, __shfl_xor(mx2, off, 64));
  unsigned lo2_b = __float_as_uint(fmaxf(v32 - 3.0f * TK_WIN, 0.f));
  unsigned hi2_b = __float_as_uint(mx2);
  while (hi2_b - lo2_b > 1u) {
    unsigned mid_b = lo2_b + ((hi2_b - lo2_b) >> 1);
    float midf = __uint_as_float(mid_b);
    int n = (int)__popcll(__ballot(q0 > midf)) + (int)__popcll(__ballot(q1 > midf))
          + (int)__popcll(__ballot(q2 > midf));
    if (n >= KSEL) lo2_b = mid_b; else hi2_b = mid_b;
  }
  const float v32x = __uint_as_float(hi2_b);

  // ---- selection: all > v32x, plus lowest-index == v32x to fill 32 ----
  const bool gA = q0 > v32x, gB = q1 > v32x, gC = q2 > v32x;
  const int ngt = (int)__popcll(__ballot(gA)) + (int)__popcll(__ballot(gB))
                + (int)__popcll(__ballot(gC));
  const int need = KSEL - ngt;              // >= 1 by bisection invariant
  const bool xA = q0 == v32x, xB = q1 == v32x, xC = q2 == v32x;
  bool sA = gA, sB = gB, sC = gC;
  {
    int ebase = 0;
    unsigned long long b = __ballot(xA);
    if (xA) { int p = ebase + (int)__popcll(b & lmask); sA = sA || (p < need); }
    ebase += (int)__popcll(b);
    b = __ballot(xB);
    if (xB) { int p = ebase + (int)__popcll(b & lmask); sB = sB || (p < need); }
    ebase += (int)__popcll(b);
    b = __ballot(xC);
    if (xC) { int p = ebase + (int)__popcll(b & lmask); sC = sC || (p < need); }
  }

  // ---- write ws (+ seli) in slot-compacted order (exactly 32 selected) ----
  {
    int sbase = 0;
    unsigned long long b = __ballot(sA);
    if (sA) { int p = sbase + (int)__popcll(b & lmask);
      ws_val[row * KSEL + p] = c0; ws_idx[row * KSEL + p] = i0; seli[wave][p] = i0; }
    sbase += (int)__popcll(b);
    b = __ballot(sB);
    if (sB) { int p = sbase + (int)__popcll(b & lmask);
      ws_val[row * KSEL + p] = c1; ws_idx[row * KSEL + p] = i1; seli[wave][p] = i1; }
    sbase += (int)__popcll(b);
    b = __ballot(sC);
    if (sC) { int p = sbase + (int)__popcll(b & lmask);
      ws_val[row * KSEL + p] = c2; ws_idx[row * KSEL + p] = i2; seli[wave][p] = i2; }
  }

  // build per-lane selection mask, write sparse row (noisy values)
  unsigned long long m = 0ull;
#pragma unroll
  for (int s = 0; s < KSEL; ++s) {
    int idx = seli[wave][s];
    if ((idx & 63) == lane) m |= 1ull << (idx >> 6);
  }
#pragma unroll
  for (int j = 0; j < 40; ++j)
    rowp[lane + 64 * j] = ((m >> j) & 1ull) ? v[j] : 0.f;
}

// ============ decoder: recon = sparse @ Wd^T + bd (bf16 WdT gather) ============
__global__ __launch_bounds__(256) void decoder_kernel(
    const float* __restrict__ ws_val,
    const int*   __restrict__ ws_idx,
    const unsigned short* __restrict__ WdT,
    const float* __restrict__ bd,
    float* __restrict__ recon)
{
  const int wave = threadIdx.x >> 6, lane = threadIdx.x & 63;
  const size_t row = (size_t)blockIdx.x * 4 + wave;

  float myv = 0.f; int myi = 0;
  if (lane < KSEL) { myv = ws_val[row * KSEL + lane]; myi = ws_idx[row * KSEL + lane]; }

  float2 acc[5];
#pragma unroll
  for (int u = 0; u < 5; ++u) acc[u] = *(const float2*)(bd + 2 * lane + 128 * u);

#pragma unroll 4
  for (int j = 0; j < KSEL; ++j) {
    float vj = __shfl(myv, j, 64);
    int   ij = __shfl(myi, j, 64);
    const unsigned short* wr = WdT + (size_t)ij * IN_DIM;
#pragma unroll
    for (int u = 0; u < 5; ++u) {
      unsigned int w2 = *(const unsigned int*)(wr + 2 * lane + 128 * u);
      acc[u].x += vj * __uint_as_float(w2 << 16);
      acc[u].y += vj * __uint_as_float(w2 & 0xffff0000u);
    }
  }
#pragma unroll
  for (int u = 0; u < 5; ++u)
    *(float2*)(recon + row * IN_DIM + 2 * lane + 128 * u) = acc[u];
}

// ============ launch ============
extern "C" void kernel_launch(void* const* d_in, const int* in_sizes, int n_in,
                              void* d_out, int out_size, void* d_ws, size_t ws_size,
                              hipStream_t stream) {
  const float* x  = (const float*)d_in[0];
  const float* We = (const float*)d_in[1];
  const float* be = (const float*)d_in[2];
  const float* Wd = (const float*)d_in[3];
  const float* bd = (const float*)d_in[4];

  float* recon  = (float*)d_out;
  float* sparse = (float*)d_out + (size_t)BATCH * IN_DIM;   // also dense-latent scratch

  char* ws = (char*)d_ws;
  float*          ws_val = (float*)ws;                                   ws += (size_t)BATCH * KSEL * 4;
  int*            ws_idx = (int*)ws;                                     ws += (size_t)BATCH * KSEL * 4;
  unsigned short* WdT    = (unsigned short*)ws;                          ws += (size_t)LAT_DIM * IN_DIM * 2;
  unsigned short* x_bf   = (unsigned short*)ws;                          ws += (size_t)BATCH * IN_DIM * 2;
  unsigned short* We_bf  = (unsigned short*)ws;

  conv_bf16    <<<(BATCH * IN_DIM / 8 + 255) / 256, 256, 0, stream>>>(x, x_bf, BATCH * IN_DIM / 8);
  conv_bf16    <<<(LAT_DIM * IN_DIM / 8 + 255) / 256, 256, 0, stream>>>(We, We_bf, LAT_DIM * IN_DIM / 8);
  transpose_wd <<<(LAT_DIM / 32) * (IN_DIM / 32), 256, 0, stream>>>(Wd, WdT);
  encoder_mfma <<<(BATCH / 128) * (LAT_DIM / 128), 256, 0, stream>>>(x_bf, We_bf, be, sparse);
  topk2        <<<BATCH / 4, 256, 0, stream>>>(sparse, x, We, be, ws_val, ws_idx);
  decoder_kernel<<<BATCH / 4, 256, 0, stream>>>(ws_val, ws_idx, WdT, bd, recon);
}

// Round 2
// 1832.213 us; speedup vs baseline: 1.3253x; 1.1731x over previous
//
#include <hip/hip_runtime.h>
#include <cstdint>

#define BATCH   65536
#define IN_DIM  640
#define LAT_DIM 2560
#define KSEL    32

typedef short  v8s __attribute__((ext_vector_type(8)));
typedef float  v4f __attribute__((ext_vector_type(4)));

__device__ inline void async_load16(void* lds, const void* g) {
  __builtin_amdgcn_global_load_lds(
      (const __attribute__((address_space(1))) unsigned int*)g,
      (__attribute__((address_space(3))) unsigned int*)lds, 16, 0, 0);
}

__device__ inline unsigned short f2bf(float v) {
  unsigned int b = __float_as_uint(v);
  return (unsigned short)((b + 0x7fffu + ((b >> 16) & 1u)) >> 16);
}

// ============ conv fp32 -> bf16, 8 elems/thread ============
__global__ __launch_bounds__(256) void conv_bf16(
    const float* __restrict__ src, unsigned short* __restrict__ dst, int n8)
{
  int i = blockIdx.x * 256 + threadIdx.x;
  if (i >= n8) return;
  const float4* s4 = (const float4*)(src) + i * 2;
  float4 a = s4[0], b = s4[1];
  ushort4 lo = make_ushort4(f2bf(a.x), f2bf(a.y), f2bf(a.z), f2bf(a.w));
  ushort4 hi = make_ushort4(f2bf(b.x), f2bf(b.y), f2bf(b.z), f2bf(b.w));
  *(ushort4*)(dst + (size_t)i * 8)     = lo;
  *(ushort4*)(dst + (size_t)i * 8 + 4) = hi;
}

// ============ transpose Wd [640][2560] -> WdT bf16 [2560][640] ============
__global__ __launch_bounds__(256) void transpose_wd(
    const float* __restrict__ Wd, unsigned short* __restrict__ WdT)
{
  __shared__ float tile[32][33];
  const int tx = threadIdx.x & 31;
  const int ty = threadIdx.x >> 5;
  const int l0 = (blockIdx.x % (LAT_DIM / 32)) * 32;
  const int i0 = (blockIdx.x / (LAT_DIM / 32)) * 32;
#pragma unroll
  for (int s = 0; s < 4; ++s)
    tile[ty + 8 * s][tx] = Wd[(size_t)(i0 + ty + 8 * s) * LAT_DIM + l0 + tx];
  __syncthreads();
#pragma unroll
  for (int s = 0; s < 4; ++s)
    WdT[(size_t)(l0 + ty + 8 * s) * IN_DIM + i0 + tx] = f2bf(tile[tx][ty + 8 * s]);
}

// ============ encoder: lat = x @ We^T + be, bf16 MFMA, fp32 out ============
__global__ __launch_bounds__(256) void encoder_mfma(
    const unsigned short* __restrict__ xb,   // bf16 [B][640]
    const unsigned short* __restrict__ web,  // bf16 [2560][640]
    const float* __restrict__ be,
    float* __restrict__ lat)                 // fp32 [B][2560]
{
  __shared__ unsigned short As[128 * 32];
  __shared__ unsigned short Bs[128 * 32];

  const int t = threadIdx.x, lane = t & 63, wave = t >> 6;
  const int nt = blockIdx.x % (LAT_DIM / 128);
  const int mt = blockIdx.x / (LAT_DIM / 128);
  const int m0 = mt * 128, n0 = nt * 128;
  const int mBase = (wave & 1) * 64, nBase = (wave >> 1) * 64;

  v4f acc[4][4];
#pragma unroll
  for (int mi = 0; mi < 4; ++mi)
#pragma unroll
    for (int ni = 0; ni < 4; ++ni) acc[mi][ni] = (v4f){0.f, 0.f, 0.f, 0.f};

  const int s1 = t, s2 = t + 256;
  const int r1 = s1 >> 2, q1 = s1 & 3, r2 = s2 >> 2, q2 = s2 & 3;
  const unsigned short* gA1 = xb  + (size_t)(m0 + r1) * IN_DIM + q1 * 8;
  const unsigned short* gA2 = xb  + (size_t)(m0 + r2) * IN_DIM + q2 * 8;
  const unsigned short* gB1 = web + (size_t)(n0 + r1) * IN_DIM + q1 * 8;
  const unsigned short* gB2 = web + (size_t)(n0 + r2) * IN_DIM + q2 * 8;
  unsigned short* lA1 = As + s1 * 8;  unsigned short* lA2 = As + s2 * 8;
  unsigned short* lB1 = Bs + s1 * 8;  unsigned short* lB2 = Bs + s2 * 8;

  const int arow = (mBase + (lane & 15)) * 32 + (lane >> 4) * 8;
  const int brow = (nBase + (lane & 15)) * 32 + (lane >> 4) * 8;

  for (int kt = 0; kt < IN_DIM; kt += 32) {
    async_load16(lA1, gA1 + kt);
    async_load16(lA2, gA2 + kt);
    async_load16(lB1, gB1 + kt);
    async_load16(lB2, gB2 + kt);
    __syncthreads();
    v8s a[4], b[4];
#pragma unroll
    for (int mi = 0; mi < 4; ++mi) a[mi] = *(const v8s*)(As + arow + mi * 16 * 32);
#pragma unroll
    for (int ni = 0; ni < 4; ++ni) b[ni] = *(const v8s*)(Bs + brow + ni * 16 * 32);
#pragma unroll
    for (int mi = 0; mi < 4; ++mi)
#pragma unroll
      for (int ni = 0; ni < 4; ++ni)
        acc[mi][ni] = __builtin_amdgcn_mfma_f32_16x16x32_bf16(a[mi], b[ni], acc[mi][ni], 0, 0, 0);
    __syncthreads();
  }

  float bev[4];
#pragma unroll
  for (int ni = 0; ni < 4; ++ni) bev[ni] = be[n0 + nBase + ni * 16 + (lane & 15)];
#pragma unroll
  for (int mi = 0; mi < 4; ++mi) {
    const int grow0 = m0 + mBase + mi * 16 + (lane >> 4) * 4;
#pragma unroll
    for (int ni = 0; ni < 4; ++ni) {
      const int gcol = n0 + nBase + ni * 16 + (lane & 15);
#pragma unroll
      for (int r = 0; r < 4; ++r)
        lat[(size_t)(grow0 + r) * LAT_DIM + gcol] = acc[mi][ni][r] + bev[ni];
    }
  }
}

// ============ topk v3: float4 memory phases, LDS-staged x, pipelined gather ====
// Selection semantics identical to v2 (threshold+compact, exact bit-bisection,
// window recompute with strictly-sequential ascending-k fp32 fma chain).
// Layout change (float4: element e = 256j + 4*lane + c) only permutes candidate
// slot order; ties in slot order occur only among exactly-equal floats, and the
// rank-31 boundary value is unique (continuous exact values), so the selected
// set is unchanged.
#define TK_CAP 160
#define TK_WIN 0.012f

__global__ __launch_bounds__(256) void topk2(
    float* __restrict__ lat,            // dense noisy in, sparse out (in place)
    const float* __restrict__ x,        // fp32 [B][640]
    const float* __restrict__ We,       // fp32 [2560][640]
    const float* __restrict__ be,
    float* __restrict__ ws_val, int* __restrict__ ws_idx)
{
  __shared__ float cval[4][TK_CAP];
  __shared__ int   cidx[4][TK_CAP];
  __shared__ int   winl[4][48];
  __shared__ int   seli[4][KSEL];
  __shared__ float xs[4][IN_DIM];     // staged x row per wave (10 KiB)

  const int wave = threadIdx.x >> 6, lane = threadIdx.x & 63;
  const size_t row = (size_t)blockIdx.x * 4 + wave;
  float* rowp = lat + row * LAT_DIM;
  const unsigned long long lmask = (1ull << lane) - 1ull;

  // ---- load latent row as float4 (10 x 1KB/wave) + stage x row to LDS ----
  v4f v[10];
  const v4f* row4 = (const v4f*)rowp;
#pragma unroll
  for (int j = 0; j < 10; ++j) v[j] = row4[lane + 64 * j];

  const float* xrow = x + row * IN_DIM;
#pragma unroll
  for (int j = 0; j < 10; ++j) xs[wave][lane + 64 * j] = xrow[lane + 64 * j];

  // ---- row RMS -> initial threshold ----
  float ss = 0.f;
#pragma unroll
  for (int j = 0; j < 10; ++j) {
    ss = fmaf(v[j][0], v[j][0], ss);
    ss = fmaf(v[j][1], v[j][1], ss);
    ss = fmaf(v[j][2], v[j][2], ss);
    ss = fmaf(v[j][3], v[j][3], ss);
  }
#pragma unroll
  for (int off = 32; off > 0; off >>= 1) ss += __shfl_xor(ss, off, 64);
  const float sigma = sqrtf(ss * (1.0f / LAT_DIM));
  float T = 1.96f * sigma;

  int cnt = 0;
  for (int it = 0; it < 40; ++it) {
    cnt = 0;
#pragma unroll
    for (int j = 0; j < 10; ++j) {
      cnt += (int)__popcll(__ballot(v[j][0] > T));
      cnt += (int)__popcll(__ballot(v[j][1] > T));
      cnt += (int)__popcll(__ballot(v[j][2] > T));
      cnt += (int)__popcll(__ballot(v[j][3] > T));
    }
    if (cnt >= 44 && cnt <= TK_CAP) break;
    T += (cnt < 44) ? (-0.25f * sigma) : (0.10f * sigma);
  }

  // ---- collect candidates via ballot compaction ----
  int base = 0;
#pragma unroll
  for (int j = 0; j < 10; ++j) {
#pragma unroll
    for (int c = 0; c < 4; ++c) {
      float val = v[j][c];
      unsigned long long b = __ballot(val > T);
      if (val > T) {
        int p = base + (int)__popcll(b & lmask);
        if (p < TK_CAP) { cval[wave][p] = val; cidx[wave][p] = 256 * j + 4 * lane + c; }
      }
      base += (int)__popcll(b);
    }
  }
  cnt = base < TK_CAP ? base : TK_CAP;

  // ---- candidates into registers: 3 slots per lane ----
  const int e0 = lane, e1 = lane + 64, e2 = lane + 128;
  float c0 = (e0 < cnt) ? cval[wave][e0] : -3e38f;
  float c1 = (e1 < cnt) ? cval[wave][e1] : -3e38f;
  float c2 = (e2 < cnt) ? cval[wave][e2] : -3e38f;
  int   i0 = (e0 < cnt) ? cidx[wave][e0] : 0;
  int   i1 = (e1 < cnt) ? cidx[wave][e1] : 0;
  int   i2 = (e2 < cnt) ? cidx[wave][e2] : 0;

  // ---- bisect 1: v32 = exact rank-31 noisy value ----
  float mx = fmaxf(fmaxf(c0, c1), c2);
#pragma unroll
  for (int off = 32; off > 0; off >>= 1) mx = fmaxf(mx, __shfl_xor(mx, off, 64));
  unsigned lo_b = __float_as_uint(fmaxf(T, 0.f));
  unsigned hi_b = __float_as_uint(mx);
  while (hi_b - lo_b > 1u) {
    unsigned mid_b = lo_b + ((hi_b - lo_b) >> 1);
    float midf = __uint_as_float(mid_b);
    int n = (int)__popcll(__ballot(c0 > midf)) + (int)__popcll(__ballot(c1 > midf))
          + (int)__popcll(__ballot(c2 > midf));
    if (n >= KSEL) lo_b = mid_b; else hi_b = mid_b;
  }
  const float v32 = __uint_as_float(hi_b);

  // ---- eligibility + window flags from NOISY values ----
  const bool el0 = (e0 < cnt) && (c0 >= v32 - TK_WIN);
  const bool el1 = (e1 < cnt) && (c1 >= v32 - TK_WIN);
  const bool el2 = (e2 < cnt) && (c2 >= v32 - TK_WIN);
  const bool w0  = (e0 < cnt) && (fabsf(c0 - v32) <= TK_WIN);
  const bool w1  = (e1 < cnt) && (fabsf(c1 - v32) <= TK_WIN);
  const bool w2  = (e2 < cnt) && (fabsf(c2 - v32) <= TK_WIN);

  int wbase = 0;
  {
    unsigned long long b = __ballot(w0);
    if (w0) { int p = wbase + (int)__popcll(b & lmask); if (p < 48) winl[wave][p] = e0; }
    wbase += (int)__popcll(b);
    b = __ballot(w1);
    if (w1) { int p = wbase + (int)__popcll(b & lmask); if (p < 48) winl[wave][p] = e1; }
    wbase += (int)__popcll(b);
    b = __ballot(w2);
    if (w2) { int p = wbase + (int)__popcll(b & lmask); if (p < 48) winl[wave][p] = e2; }
    wbase += (int)__popcll(b);
  }
  const int wcnt = wbase < 48 ? wbase : 48;

  // ---- exact recompute: sequential ascending-k fp32 fma chain ----
  // x from LDS (broadcast ds_read_b128), We gather software-pipelined.
  if (lane < wcnt) {
    int slot = winl[wave][lane];
    int c = cidx[wave][slot];
    const v4f* w4 = (const v4f*)(We + (size_t)c * IN_DIM);
    const float* xsr = xs[wave];
    float acc = 0.f;
    v4f wv = w4[0];
#pragma unroll 8
    for (int i = 0; i < IN_DIM / 4 - 1; ++i) {
      v4f wn = w4[i + 1];
      v4f xv = *(const v4f*)(xsr + 4 * i);
      acc = fmaf(xv[0], wv[0], acc);
      acc = fmaf(xv[1], wv[1], acc);
      acc = fmaf(xv[2], wv[2], acc);
      acc = fmaf(xv[3], wv[3], acc);
      wv = wn;
    }
    {
      v4f xv = *(const v4f*)(xsr + IN_DIM - 4);
      acc = fmaf(xv[0], wv[0], acc);
      acc = fmaf(xv[1], wv[1], acc);
      acc = fmaf(xv[2], wv[2], acc);
      acc = fmaf(xv[3], wv[3], acc);
    }
    cval[wave][slot] = acc + be[c];
  }

  // refresh registers with substituted values
  if (e0 < cnt) c0 = cval[wave][e0];
  if (e1 < cnt) c1 = cval[wave][e1];
  if (e2 < cnt) c2 = cval[wave][e2];

  // ---- bisect 2: exact rank-31 among ELIGIBLE with substituted values ----
  const float q0 = el0 ? c0 : -3e38f;
  const float q1 = el1 ? c1 : -3e38f;
  const float q2 = el2 ? c2 : -3e38f;
  float mx2 = fmaxf(fmaxf(q0, q1), q2);
#pragma unroll
  for (int off = 32; off > 0; off >>= 1) mx2 = fmaxf(mx2, __shfl_xor(mx2, off, 64));
  unsigned lo2_b = __float_as_uint(fmaxf(v32 - 3.0f * TK_WIN, 0.f));
  unsigned hi2_b = __float_as_uint(mx2);
  while (hi2_b - lo2_b > 1u) {
    unsigned mid_b = lo2_b + ((hi2_b - lo2_b) >> 1);
    float midf = __uint_as_float(mid_b);
    int n = (int)__popcll(__ballot(q0 > midf)) + (int)__popcll(__ballot(q1 > midf))
          + (int)__popcll(__ballot(q2 > midf));
    if (n >= KSEL) lo2_b = mid_b; else hi2_b = mid_b;
  }
  const float v32x = __uint_as_float(hi2_b);

  // ---- selection: all > v32x, plus lowest-slot == v32x to fill 32 ----
  const bool gA = q0 > v32x, gB = q1 > v32x, gC = q2 > v32x;
  const int ngt = (int)__popcll(__ballot(gA)) + (int)__popcll(__ballot(gB))
                + (int)__popcll(__ballot(gC));
  const int need = KSEL - ngt;
  const bool xA = q0 == v32x, xB = q1 == v32x, xC = q2 == v32x;
  bool sA = gA, sB = gB, sC = gC;
  {
    int ebase = 0;
    unsigned long long b = __ballot(xA);
    if (xA) { int p = ebase + (int)__popcll(b & lmask); sA = sA || (p < need); }
    ebase += (int)__popcll(b);
    b = __ballot(xB);
    if (xB) { int p = ebase + (int)__popcll(b & lmask); sB = sB || (p < need); }
    ebase += (int)__popcll(b);
    b = __ballot(xC);
    if (xC) { int p = ebase + (int)__popcll(b & lmask); sC = sC || (p < need); }
  }

  // ---- write ws (+ seli) in slot-compacted order (exactly 32 selected) ----
  {
    int sbase = 0;
    unsigned long long b = __ballot(sA);
    if (sA) { int p = sbase + (int)__popcll(b & lmask);
      ws_val[row * KSEL + p] = c0; ws_idx[row * KSEL + p] = i0; seli[wave][p] = i0; }
    sbase += (int)__popcll(b);
    b = __ballot(sB);
    if (sB) { int p = sbase + (int)__popcll(b & lmask);
      ws_val[row * KSEL + p] = c1; ws_idx[row * KSEL + p] = i1; seli[wave][p] = i1; }
    sbase += (int)__popcll(b);
    b = __ballot(sC);
    if (sC) { int p = sbase + (int)__popcll(b & lmask);
      ws_val[row * KSEL + p] = c2; ws_idx[row * KSEL + p] = i2; seli[wave][p] = i2; }
  }

  // ---- build per-lane float4 selection mask, write sparse row ----
  // element e = 256j + 4l + c: owner lane = (e>>2)&63, bit = (e>>8)*4 + (e&3)
  unsigned long long m = 0ull;
#pragma unroll
  for (int s = 0; s < KSEL; ++s) {
    int idx = seli[wave][s];
    if (((idx >> 2) & 63) == lane) m |= 1ull << ((idx >> 8) * 4 + (idx & 3));
  }
  v4f* out4 = (v4f*)rowp;
#pragma unroll
  for (int j = 0; j < 10; ++j) {
    v4f o;
    o[0] = ((m >> (4 * j + 0)) & 1ull) ? v[j][0] : 0.f;
    o[1] = ((m >> (4 * j + 1)) & 1ull) ? v[j][1] : 0.f;
    o[2] = ((m >> (4 * j + 2)) & 1ull) ? v[j][2] : 0.f;
    o[3] = ((m >> (4 * j + 3)) & 1ull) ? v[j][3] : 0.f;
    out4[lane + 64 * j] = o;
  }
}

// ============ decoder: recon = sparse @ Wd^T + bd (bf16 WdT gather) ============
__global__ __launch_bounds__(256) void decoder_kernel(
    const float* __restrict__ ws_val,
    const int*   __restrict__ ws_idx,
    const unsigned short* __restrict__ WdT,
    const float* __restrict__ bd,
    float* __restrict__ recon)
{
  const int wave = threadIdx.x >> 6, lane = threadIdx.x & 63;
  const size_t row = (size_t)blockIdx.x * 4 + wave;

  float myv = 0.f; int myi = 0;
  if (lane < KSEL) { myv = ws_val[row * KSEL + lane]; myi = ws_idx[row * KSEL + lane]; }

  float2 acc[5];
#pragma unroll
  for (int u = 0; u < 5; ++u) acc[u] = *(const float2*)(bd + 2 * lane + 128 * u);

#pragma unroll 4
  for (int j = 0; j < KSEL; ++j) {
    float vj = __shfl(myv, j, 64);
    int   ij = __shfl(myi, j, 64);
    const unsigned short* wr = WdT + (size_t)ij * IN_DIM;
#pragma unroll
    for (int u = 0; u < 5; ++u) {
      unsigned int w2 = *(const unsigned int*)(wr + 2 * lane + 128 * u);
      acc[u].x += vj * __uint_as_float(w2 << 16);
      acc[u].y += vj * __uint_as_float(w2 & 0xffff0000u);
    }
  }
#pragma unroll
  for (int u = 0; u < 5; ++u)
    *(float2*)(recon + row * IN_DIM + 2 * lane + 128 * u) = acc[u];
}

// ============ launch ============
extern "C" void kernel_launch(void* const* d_in, const int* in_sizes, int n_in,
                              void* d_out, int out_size, void* d_ws, size_t ws_size,
                              hipStream_t stream) {
  const float* x  = (const float*)d_in[0];
  const float* We = (const float*)d_in[1];
  const float* be = (const float*)d_in[2];
  const float* Wd = (const float*)d_in[3];
  const float* bd = (const float*)d_in[4];

  float* recon  = (float*)d_out;
  float* sparse = (float*)d_out + (size_t)BATCH * IN_DIM;   // also dense-latent scratch

  char* ws = (char*)d_ws;
  float*          ws_val = (float*)ws;                                   ws += (size_t)BATCH * KSEL * 4;
  int*            ws_idx = (int*)ws;                                     ws += (size_t)BATCH * KSEL * 4;
  unsigned short* WdT    = (unsigned short*)ws;                          ws += (size_t)LAT_DIM * IN_DIM * 2;
  unsigned short* x_bf   = (unsigned short*)ws;                          ws += (size_t)BATCH * IN_DIM * 2;
  unsigned short* We_bf  = (unsigned short*)ws;

  conv_bf16    <<<(BATCH * IN_DIM / 8 + 255) / 256, 256, 0, stream>>>(x, x_bf, BATCH * IN_DIM / 8);
  conv_bf16    <<<(LAT_DIM * IN_DIM / 8 + 255) / 256, 256, 0, stream>>>(We, We_bf, LAT_DIM * IN_DIM / 8);
  transpose_wd <<<(LAT_DIM / 32) * (IN_DIM / 32), 256, 0, stream>>>(Wd, WdT);
  encoder_mfma <<<(BATCH / 128) * (LAT_DIM / 128), 256, 0, stream>>>(x_bf, We_bf, be, sparse);
  topk2        <<<BATCH / 4, 256, 0, stream>>>(sparse, x, We, be, ws_val, ws_idx);
  decoder_kernel<<<BATCH / 4, 256, 0, stream>>>(ws_val, ws_idx, WdT, bd, recon);
}